// Round 9
// baseline (44.304 us; speedup 1.0000x reference)
//
#include <hip/hip_runtime.h>

// Window_Crop: per-batch sliding-window average pooling over 5 aspect ratios
// (stride 1) + argmax over first 4 ratio groups.
//
// Ratios (exact Python float semantics: 1024 // 25.6 == 39.0):
//   (32,32) N=6561  off 0
//   (25,39) N=6512  off 6561
//   (39,25) N=6512  off 13073
//   (38,26) N=6525  off 19585
//   (26,38) N=6525  off 26110   (excluded from argmax)
//   total 32635
//
// R1-R7 evidence: per-image block latency ~20 us regardless of occupancy;
// throughput = images-in-flight/CU / 20 us; 3 in flight hits the ~6.6 us/img
// per-CU memory floor (R3) but tailed. This version: grid=256 (1 block/CU,
// perfectly balanced), 1024 threads, THREE 51 KB LDS integral buffers
// (153 KB dynamic), software-pipelined: windows(n) || rowscan(n+1) ||
// loads(n+2) in flight, colscan(n+1) + write_img(n+2) after mid-barrier.
// 2 barriers per image. (R8 fix: no LDS pointer array -- gfx950 rejects the
// addrspacecast static initializer; compute smem + (n%3)*ISZ instead.)

#define B_TOTAL 1024
#define GRID    256
#define IMGS    4                    // images per block
#define HW      112
#define NPIX    (HW * HW)
#define NV4     (NPIX / 4)           // 3136 float4 per image
#define PITCH   113
#define ISZ     (PITCH * PITCH)      // 12769 floats = 51,076 B per buffer
#define TOTAL_W 32635
#define BLOCK   1024
#define LDV4    4                    // ceil(3136 / 1024)
#define SEG     28                   // 112 / 4 segments per scan line

template<int KH, int KW, int OFF, bool TRACK>
__device__ __forceinline__ void windows_group(const float* __restrict__ S,
                                              float* __restrict__ out_scores,
                                              int tid, float& bestv, int& besti) {
    constexpr int OH = HW - KH + 1;
    constexpr int OW = HW - KW + 1;
    constexpr int N  = OH * OW;
    constexpr int D  = KH * PITCH;        // bottom-row offset (dwords)
    constexpr float inv = 1.0f / (float)(KH * KW);
    for (int w = tid; w < N; w += BLOCK) {
        const int i  = w / OW;            // const divisor -> magic mul
        const int j  = w - i * OW;
        const int A  = i * PITCH + j;     // top-left corner
        const int Ab = A + D;             // bottom-left corner
        const float s = S[Ab + KW] - S[A + KW] - S[Ab] + S[A];
        const float sc = s * inv;
        out_scores[OFF + w] = sc;         // lanes stride-1: packed 256B/wave
        if (TRACK && sc > bestv) { bestv = sc; besti = OFF + w; }
    }
}

__device__ __forceinline__ void load_regs(const float* __restrict__ x, int b,
                                          int tid, float4* v) {
    const float4* img = (const float4*)(x + (size_t)b * NPIX);
    #pragma unroll
    for (int k = 0; k < LDV4; ++k) {
        const int i = tid + k * BLOCK;
        if (i < NV4) v[k] = img[i];
    }
}

__device__ __forceinline__ void write_img(float* __restrict__ S, const float4* v,
                                          int tid) {
    #pragma unroll
    for (int k = 0; k < LDV4; ++k) {
        const int i = tid + k * BLOCK;
        if (i < NV4) {
            const int r = i / (HW / 4);
            const int c = (i - r * (HW / 4)) * 4;
            float* dst = &S[(r + 1) * PITCH + (c + 1)];
            dst[0] = v[k].x; dst[1] = v[k].y; dst[2] = v[k].z; dst[3] = v[k].w;
        }
    }
}

__device__ __forceinline__ void rowscan(float* __restrict__ S, int tid, int bl) {
    // 112 rows x 4 segments of 28; partials in regs, shfl fixup.
    // Across threads addresses stride PITCH=113: gcd(113,32)=1 -> conflict-free.
    if (tid < HW * 4) {
        const int r = tid >> 2, s = tid & 3;
        float* row = &S[(r + 1) * PITCH];
        const int c0 = 1 + s * SEG;
        float pref[SEG];
        float run = 0.0f;
        #pragma unroll
        for (int k = 0; k < SEG; ++k) { run += row[c0 + k]; pref[k] = run; }
        const float v0 = __shfl(run, bl, 64), v1 = __shfl(run, bl + 1, 64),
                    v2 = __shfl(run, bl + 2, 64);
        float off = 0.0f;
        if (s > 0) off += v0;
        if (s > 1) off += v1;
        if (s > 2) off += v2;
        #pragma unroll
        for (int k = 0; k < SEG; ++k) row[c0 + k] = pref[k] + off;
    }
}

__device__ __forceinline__ void colscan(float* __restrict__ S, int tid, int bl) {
    if (tid < HW * 4) {
        const int c = tid >> 2, s = tid & 3;
        float* col = &S[c + 1];
        const int r0 = 1 + s * SEG;
        float pref[SEG];
        float run = 0.0f;
        #pragma unroll
        for (int k = 0; k < SEG; ++k) { run += col[(r0 + k) * PITCH]; pref[k] = run; }
        const float v0 = __shfl(run, bl, 64), v1 = __shfl(run, bl + 1, 64),
                    v2 = __shfl(run, bl + 2, 64);
        float off = 0.0f;
        if (s > 0) off += v0;
        if (s > 1) off += v1;
        if (s > 2) off += v2;
        #pragma unroll
        for (int k = 0; k < SEG; ++k) col[(r0 + k) * PITCH] = pref[k] + off;
    }
}

__device__ __forceinline__ void windows_all(const float* __restrict__ S,
                                            float* __restrict__ out, int b,
                                            int tid, int lane,
                                            float* wv, int* wi) {
    float bestv = -3.402823466e+38f;
    int   besti = 0;
    float* out_scores = out + 2 * B_TOTAL + (size_t)b * TOTAL_W;

    windows_group<32, 32,     0, true >(S, out_scores, tid, bestv, besti);
    windows_group<25, 39,  6561, true >(S, out_scores, tid, bestv, besti);
    windows_group<39, 25, 13073, true >(S, out_scores, tid, bestv, besti);
    windows_group<38, 26, 19585, true >(S, out_scores, tid, bestv, besti);
    windows_group<26, 38, 26110, false>(S, out_scores, tid, bestv, besti);

    #pragma unroll
    for (int d = 32; d > 0; d >>= 1) {
        const float ov = __shfl_down(bestv, d, 64);
        const int   oi = __shfl_down(besti, d, 64);
        if (ov > bestv || (ov == bestv && oi < besti)) { bestv = ov; besti = oi; }
    }
    if (lane == 0) { wv[tid >> 6] = bestv; wi[tid >> 6] = besti; }
}

__device__ __forceinline__ void final_reduce(float* __restrict__ out, int b,
                                             int tid, const float* wv,
                                             const int* wi) {
    if (tid == 0) {
        float bv = wv[0]; int bi = wi[0];
        #pragma unroll
        for (int k = 1; k < BLOCK / 64; ++k) {
            if (wv[k] > bv || (wv[k] == bv && wi[k] < bi)) { bv = wv[k]; bi = wi[k]; }
        }
        out[b]           = (float)bi;    // idx (exact in fp32: < 2^24)
        out[B_TOTAL + b] = bv;           // prop_scores
    }
}

__global__ __launch_bounds__(BLOCK, 4)
void window_crop_kernel(const float* __restrict__ x, float* __restrict__ out) {
    extern __shared__ float smem[];              // 3 x 12769 floats
    __shared__ float wv[BLOCK / 64];
    __shared__ int   wi[BLOCK / 64];

    const int tid  = threadIdx.x;
    const int lane = tid & 63;
    const int bl   = lane & ~3;
    const int b0   = blockIdx.x * IMGS;

    // zero border row/col of all 3 buffers (never touched again)
    for (int i = tid; i < PITCH; i += BLOCK) {
        smem[i]               = 0.0f; smem[i * PITCH]           = 0.0f;
        smem[ISZ + i]         = 0.0f; smem[ISZ + i * PITCH]     = 0.0f;
        smem[2 * ISZ + i]     = 0.0f; smem[2 * ISZ + i * PITCH] = 0.0f;
    }

    float4 v[LDV4];

    // ---- prologue: image 0 scanned, image 1 raw-written ----
    load_regs(x, b0 + 0, tid, v);
    write_img(smem, v, tid);
    __syncthreads();
    rowscan(smem, tid, bl);
    __syncthreads();
    colscan(smem, tid, bl);
    load_regs(x, b0 + 1, tid, v);
    write_img(smem + ISZ, v, tid);    // different buffer than colscan -> no race
    __syncthreads();

    // ---- steady state: windows(n) || rowscan(n+1), loads(n+2) in flight ----
    for (int n = 0; n < IMGS; ++n) {
        float* Sn = smem + (n % 3) * ISZ;
        if (n + 2 < IMGS) load_regs(x, b0 + n + 2, tid, v);        // issue early
        windows_all(Sn, out, b0 + n, tid, lane, wv, wi);           // store phase
        if (n + 1 < IMGS) rowscan(smem + ((n + 1) % 3) * ISZ, tid, bl);
        __syncthreads();
        final_reduce(out, b0 + n, tid, wv, wi);
        if (n + 1 < IMGS) colscan(smem + ((n + 1) % 3) * ISZ, tid, bl);
        if (n + 2 < IMGS) write_img(smem + ((n + 2) % 3) * ISZ, v, tid);
        __syncthreads();
    }
}

extern "C" void kernel_launch(void* const* d_in, const int* in_sizes, int n_in,
                              void* d_out, int out_size, void* d_ws, size_t ws_size,
                              hipStream_t stream) {
    const float* x = (const float*)d_in[0];
    float* out     = (float*)d_out;
    window_crop_kernel<<<GRID, BLOCK, 3 * ISZ * sizeof(float), stream>>>(x, out);
}